// Round 5
// baseline (457.838 us; speedup 1.0000x reference)
//
#include <hip/hip_runtime.h>
#include <hip/hip_bf16.h>
#include <math.h>

#define BATCH 8192
#define INSZ 784
#define SYS 1024
#define OUTSZ 10
#define NSTEP 100
#define HSTEP 0.01f
#define FFORCE 8.0f

typedef short short8 __attribute__((ext_vector_type(8)));
typedef float float4v __attribute__((ext_vector_type(4)));
typedef float v2f __attribute__((ext_vector_type(2)));

static __device__ __forceinline__ short f2bf(float x) {
    __hip_bfloat16 b = __float2bfloat16(x);   // RNE
    return __builtin_bit_cast(short, b);
}
static __device__ __forceinline__ float bf2f(short s) {
    unsigned int u = ((unsigned int)(unsigned short)s) << 16;
    return __builtin_bit_cast(float, u);
}

static __device__ __forceinline__ v2f pkfma(v2f a, v2f b, v2f c) {
    return __builtin_elementwise_fma(a, b, c);
}
static __device__ __forceinline__ v2f mk2(float x, float y) {
    v2f r; r.x = x; r.y = y; return r;
}
static __device__ __forceinline__ v2f swp(v2f v) {
    return __builtin_shufflevector(v, v, 1, 0);
}

// DPP whole-wave rotates: full VALU-rate cross-lane, no DS pipe / lgkmcnt.
// wave_ror:1 (0x13C): D[n] = S[(n-1) & 63]   (replaces shuffle-from-laneL)
// wave_rol:1 (0x134): D[n] = S[(n+1) & 63]   (replaces shuffle-from-laneR)
static __device__ __forceinline__ float dpp_ror1(float v) {
    int i = __builtin_bit_cast(int, v);
    int r = __builtin_amdgcn_update_dpp(i, i, 0x13C, 0xF, 0xF, false);
    return __builtin_bit_cast(float, r);
}
static __device__ __forceinline__ float dpp_rol1(float v) {
    int i = __builtin_bit_cast(int, v);
    int r = __builtin_amdgcn_update_dpp(i, i, 0x134, 0xF, 0xF, false);
    return __builtin_bit_cast(float, r);
}
static __device__ __forceinline__ v2f ror1_pair(v2f v) {
    v2f r; r.x = dpp_ror1(v.x); r.y = dpp_ror1(v.y); return r;
}
static __device__ __forceinline__ v2f rol1_pair(v2f v) {
    v2f r; r.x = dpp_rol1(v.x); r.y = dpp_rol1(v.y); return r;
}

// ---------------------------------------------------------------------------
// GEMM1 (unchanged from round 2): h = x @ W1^T + b1, split-bf16 MFMA.
// ---------------------------------------------------------------------------
#define BMg 128
#define BNg 128
#define BKg 32
#define LDK 40

__global__ __launch_bounds__(256, 3) void gemm1_kernel(
    const float* __restrict__ x, const float* __restrict__ W1,
    const float* __restrict__ b1, float* __restrict__ h)
{
    __shared__ short Ah[BMg * LDK], Al[BMg * LDK];
    __shared__ short Bh[BNg * LDK], Bl[BNg * LDK];

    const int t  = threadIdx.x;
    const int bm = blockIdx.y * BMg;
    const int bn = blockIdx.x * BNg;

    const int srow = t >> 1;
    const int kq   = (t & 1) * 16;

    const int wv   = t >> 6;
    const int lane = t & 63;
    const int lm   = lane & 15;
    const int q    = lane >> 4;
    const int rb   = (wv & 1) * 64;
    const int cb   = (wv >> 1) * 64;

    float4v acc[4][4];
    #pragma unroll
    for (int i = 0; i < 4; ++i)
        #pragma unroll
        for (int j = 0; j < 4; ++j) {
            acc[i][j][0] = 0.f; acc[i][j][1] = 0.f;
            acc[i][j][2] = 0.f; acc[i][j][3] = 0.f;
        }

    const float* xa0 = x  + (size_t)(bm + srow) * INSZ + kq;
    const float* wb0 = W1 + (size_t)(bn + srow) * INSZ + kq;

    for (int it = 0; it < 25; ++it) {
        const int k0 = it * BKg;
        {
            const bool valid = (k0 + kq) < INSZ;
            float va[16], vb[16];
            if (valid) {
                #pragma unroll
                for (int p = 0; p < 4; ++p) {
                    float4 xv = ((const float4*)(xa0 + k0))[p];
                    float4 bv = ((const float4*)(wb0 + k0))[p];
                    va[4*p+0] = xv.x; va[4*p+1] = xv.y; va[4*p+2] = xv.z; va[4*p+3] = xv.w;
                    vb[4*p+0] = bv.x; vb[4*p+1] = bv.y; vb[4*p+2] = bv.z; vb[4*p+3] = bv.w;
                }
            } else {
                #pragma unroll
                for (int j = 0; j < 16; ++j) { va[j] = 0.f; vb[j] = 0.f; }
            }
            short8 ahi[2], alo[2], bhi[2], blo[2];
            #pragma unroll
            for (int j = 0; j < 16; ++j) {
                short h1 = f2bf(va[j]);
                short l1 = f2bf(va[j] - bf2f(h1));
                short h2 = f2bf(vb[j]);
                short l2 = f2bf(vb[j] - bf2f(h2));
                ahi[j >> 3][j & 7] = h1;  alo[j >> 3][j & 7] = l1;
                bhi[j >> 3][j & 7] = h2;  blo[j >> 3][j & 7] = l2;
            }
            const int base = srow * LDK + kq;
            *(short8*)&Ah[base] = ahi[0];  *(short8*)&Ah[base + 8] = ahi[1];
            *(short8*)&Al[base] = alo[0];  *(short8*)&Al[base + 8] = alo[1];
            *(short8*)&Bh[base] = bhi[0];  *(short8*)&Bh[base + 8] = bhi[1];
            *(short8*)&Bl[base] = blo[0];  *(short8*)&Bl[base + 8] = blo[1];
        }
        __syncthreads();

        short8 bhf[4], blf[4];
        #pragma unroll
        for (int fj = 0; fj < 4; ++fj) {
            const int off = (cb + fj * 16 + lm) * LDK + q * 8;
            bhf[fj] = *(const short8*)&Bh[off];
            blf[fj] = *(const short8*)&Bl[off];
        }
        #pragma unroll
        for (int fi = 0; fi < 4; ++fi) {
            const int off = (rb + fi * 16 + lm) * LDK + q * 8;
            short8 ah = *(const short8*)&Ah[off];
            short8 al = *(const short8*)&Al[off];
            #pragma unroll
            for (int fj = 0; fj < 4; ++fj) {
                acc[fi][fj] = __builtin_amdgcn_mfma_f32_16x16x32_bf16(ah, bhf[fj], acc[fi][fj], 0, 0, 0);
                acc[fi][fj] = __builtin_amdgcn_mfma_f32_16x16x32_bf16(ah, blf[fj], acc[fi][fj], 0, 0, 0);
                acc[fi][fj] = __builtin_amdgcn_mfma_f32_16x16x32_bf16(al, bhf[fj], acc[fi][fj], 0, 0, 0);
            }
        }
        __syncthreads();
    }

    #pragma unroll
    for (int fj = 0; fj < 4; ++fj) {
        const int col  = bn + cb + fj * 16 + lm;
        const float bias = b1[col];
        #pragma unroll
        for (int fi = 0; fi < 4; ++fi) {
            const int row0 = bm + rb + fi * 16 + q * 4;
            #pragma unroll
            for (int r = 0; r < 4; ++r)
                h[(size_t)(row0 + r) * SYS + col] = acc[fi][fj][r] + bias;
        }
    }
}

// ---------------------------------------------------------------------------
// RK4 Lorenz-96 + GEMM2 + log_softmax; packed fp32 + DPP wave-rotate halos.
// Pairing: pair p = (y[p], y[p+512]); +1 element shift == +1 pair shift with
// a component-swap twist at the 512-pair wrap (lanes 0/63 only, cndmask).
// Halos now via v_mov_b32 dpp wave_ror/rol:1 (was ds_bpermute): same values,
// same order, zero DS traffic.
// ---------------------------------------------------------------------------
__global__ __launch_bounds__(256, 4) void rk4_kernel(
    const float* __restrict__ hbuf, const float* __restrict__ W2,
    const float* __restrict__ b2, float* __restrict__ out)
{
    const int lane = threadIdx.x & 63;
    const int w    = threadIdx.x >> 6;
    const int row  = blockIdx.x * 4 + w;

    const bool atL  = (lane == 0);
    const bool atR  = (lane == 63);

    v2f X[8];
    {
        const float4* b4 = (const float4*)(hbuf + (size_t)row * SYS);
        float4 a0 = b4[lane * 2], a1 = b4[lane * 2 + 1];
        float4 c0 = b4[128 + lane * 2], c1 = b4[129 + lane * 2];
        X[0] = mk2(a0.x, c0.x); X[1] = mk2(a0.y, c0.y);
        X[2] = mk2(a0.z, c0.z); X[3] = mk2(a0.w, c0.w);
        X[4] = mk2(a1.x, c1.x); X[5] = mk2(a1.y, c1.y);
        X[6] = mk2(a1.z, c1.z); X[7] = mk2(a1.w, c1.w);
    }

    const v2f Fv = mk2(FFORCE, FFORCE);
    v2f acc[8], T[8];

    // in-place derivative on y[8]
    auto deriv_ip = [&](v2f (&y)[8]) {
        v2f r1 = rol1_pair(y[0]);  r1 = atR ? swp(r1) : r1;
        v2f l1 = ror1_pair(y[7]);  l1 = atL ? swp(l1) : l1;
        v2f l2 = ror1_pair(y[6]);  l2 = atL ? swp(l2) : l2;
        v2f p2 = l2, p1 = l1, cur = y[0];
        #pragma unroll
        for (int i = 0; i < 8; ++i) {
            v2f yp1 = (i < 7) ? y[i + 1] : r1;
            v2f nv  = pkfma(yp1 - p2, p1, Fv - cur);
            p2 = p1; p1 = cur;
            if (i < 7) cur = y[i + 1];
            y[i] = nv;
        }
    };

    const v2f c_half = mk2(0.5f * HSTEP, 0.5f * HSTEP);
    const v2f c_full = mk2(HSTEP, HSTEP);
    const v2f c_two  = mk2(2.0f, 2.0f);
    const v2f c_six  = mk2(HSTEP / 6.0f, HSTEP / 6.0f);

    #pragma unroll 1
    for (int s = 0; s < NSTEP; ++s) {
        // k1 = deriv(X) out-of-place into acc (X stays live)
        {
            v2f r1 = rol1_pair(X[0]);  r1 = atR ? swp(r1) : r1;
            v2f l1 = ror1_pair(X[7]);  l1 = atL ? swp(l1) : l1;
            v2f l2 = ror1_pair(X[6]);  l2 = atL ? swp(l2) : l2;
            #pragma unroll
            for (int i = 0; i < 8; ++i) {
                v2f yp1 = (i < 7) ? X[i + 1] : r1;
                v2f ym1 = (i > 0) ? X[i - 1] : l1;
                v2f ym2 = (i > 1) ? X[i - 2] : ((i == 1) ? l1 : l2);
                acc[i] = pkfma(yp1 - ym2, ym1, Fv - X[i]);
            }
        }
        #pragma unroll
        for (int i = 0; i < 8; ++i) T[i] = pkfma(c_half, acc[i], X[i]);
        deriv_ip(T);                                    // T = k2
        #pragma unroll
        for (int i = 0; i < 8; ++i) {
            acc[i] = pkfma(c_two, T[i], acc[i]);
            T[i]   = pkfma(c_half, T[i], X[i]);
        }
        deriv_ip(T);                                    // T = k3
        #pragma unroll
        for (int i = 0; i < 8; ++i) {
            acc[i] = pkfma(c_two, T[i], acc[i]);
            T[i]   = pkfma(c_full, T[i], X[i]);
        }
        deriv_ip(T);                                    // T = k4
        #pragma unroll
        for (int i = 0; i < 8; ++i)
            X[i] = pkfma(c_six, acc[i] + T[i], X[i]);
    }

    // GEMM2 + log_softmax epilogue (packed dot, then wave reduce)
    float l[OUTSZ];
    #pragma unroll
    for (int o = 0; o < OUTSZ; ++o) {
        const float4* w4 = (const float4*)(W2 + (size_t)o * SYS);
        float4 wa0 = w4[lane * 2], wa1 = w4[lane * 2 + 1];
        float4 wc0 = w4[128 + lane * 2], wc1 = w4[129 + lane * 2];
        v2f s2 = mk2(0.f, 0.f);
        s2 = pkfma(X[0], mk2(wa0.x, wc0.x), s2);
        s2 = pkfma(X[1], mk2(wa0.y, wc0.y), s2);
        s2 = pkfma(X[2], mk2(wa0.z, wc0.z), s2);
        s2 = pkfma(X[3], mk2(wa0.w, wc0.w), s2);
        s2 = pkfma(X[4], mk2(wa1.x, wc1.x), s2);
        s2 = pkfma(X[5], mk2(wa1.y, wc1.y), s2);
        s2 = pkfma(X[6], mk2(wa1.z, wc1.z), s2);
        s2 = pkfma(X[7], mk2(wa1.w, wc1.w), s2);
        float s = s2.x + s2.y;
        #pragma unroll
        for (int dlt = 1; dlt < 64; dlt <<= 1) s += __shfl_xor(s, dlt);
        l[o] = s + b2[o];
    }

    float m = l[0];
    #pragma unroll
    for (int o = 1; o < OUTSZ; ++o) m = fmaxf(m, l[o]);
    float ssum = 0.f;
    #pragma unroll
    for (int o = 0; o < OUTSZ; ++o) ssum += __expf(l[o] - m);
    const float lse = m + __logf(ssum);

    float v = l[0] - lse;
    #pragma unroll
    for (int o = 1; o < OUTSZ; ++o)
        if (lane == o) v = l[o] - lse;
    if (lane < OUTSZ)
        out[(size_t)row * OUTSZ + lane] = v;
}

extern "C" void kernel_launch(void* const* d_in, const int* in_sizes, int n_in,
                              void* d_out, int out_size, void* d_ws, size_t ws_size,
                              hipStream_t stream)
{
    const float* x  = (const float*)d_in[0];
    const float* W1 = (const float*)d_in[1];
    const float* b1 = (const float*)d_in[2];
    const float* W2 = (const float*)d_in[3];
    const float* b2 = (const float*)d_in[4];
    float* out = (float*)d_out;
    float* h   = (float*)d_ws;   // 8192*1024*4 = 33.5 MB scratch

    dim3 g1(SYS / BNg, BATCH / BMg);   // 8 x 64 = 512 blocks
    gemm1_kernel<<<g1, 256, 0, stream>>>(x, W1, b1, h);

    rk4_kernel<<<BATCH / 4, 256, 0, stream>>>(h, W2, b2, out);
}

// Round 6
// 431.440 us; speedup vs baseline: 1.0612x; 1.0612x over previous
//
#include <hip/hip_runtime.h>
#include <hip/hip_bf16.h>
#include <math.h>

#define BATCH 8192
#define INSZ 784
#define SYS 1024
#define OUTSZ 10
#define NSTEP 100
#define HSTEP 0.01f
#define FFORCE 8.0f

typedef short short8 __attribute__((ext_vector_type(8)));
typedef float float4v __attribute__((ext_vector_type(4)));
typedef float v2f __attribute__((ext_vector_type(2)));

static __device__ __forceinline__ short f2bf(float x) {
    __hip_bfloat16 b = __float2bfloat16(x);   // RNE
    return __builtin_bit_cast(short, b);
}
static __device__ __forceinline__ float bf2f(short s) {
    unsigned int u = ((unsigned int)(unsigned short)s) << 16;
    return __builtin_bit_cast(float, u);
}

static __device__ __forceinline__ v2f pkfma(v2f a, v2f b, v2f c) {
    return __builtin_elementwise_fma(a, b, c);
}
static __device__ __forceinline__ v2f mk2(float x, float y) {
    v2f r; r.x = x; r.y = y; return r;
}
// halo transport on the DS pipe (overlaps with VALU; DPP regressed — r5)
static __device__ __forceinline__ v2f sh2(v2f v, int ln) {
    v2f r; r.x = __shfl(v.x, ln); r.y = __shfl(v.y, ln); return r;
}

// ---------------------------------------------------------------------------
// GEMM1 (unchanged from round 2): h = x @ W1^T + b1, split-bf16 MFMA.
// ---------------------------------------------------------------------------
#define BMg 128
#define BNg 128
#define BKg 32
#define LDK 40

__global__ __launch_bounds__(256, 3) void gemm1_kernel(
    const float* __restrict__ x, const float* __restrict__ W1,
    const float* __restrict__ b1, float* __restrict__ h)
{
    __shared__ short Ah[BMg * LDK], Al[BMg * LDK];
    __shared__ short Bh[BNg * LDK], Bl[BNg * LDK];

    const int t  = threadIdx.x;
    const int bm = blockIdx.y * BMg;
    const int bn = blockIdx.x * BNg;

    const int srow = t >> 1;
    const int kq   = (t & 1) * 16;

    const int wv   = t >> 6;
    const int lane = t & 63;
    const int lm   = lane & 15;
    const int q    = lane >> 4;
    const int rb   = (wv & 1) * 64;
    const int cb   = (wv >> 1) * 64;

    float4v acc[4][4];
    #pragma unroll
    for (int i = 0; i < 4; ++i)
        #pragma unroll
        for (int j = 0; j < 4; ++j) {
            acc[i][j][0] = 0.f; acc[i][j][1] = 0.f;
            acc[i][j][2] = 0.f; acc[i][j][3] = 0.f;
        }

    const float* xa0 = x  + (size_t)(bm + srow) * INSZ + kq;
    const float* wb0 = W1 + (size_t)(bn + srow) * INSZ + kq;

    for (int it = 0; it < 25; ++it) {
        const int k0 = it * BKg;
        {
            const bool valid = (k0 + kq) < INSZ;
            float va[16], vb[16];
            if (valid) {
                #pragma unroll
                for (int p = 0; p < 4; ++p) {
                    float4 xv = ((const float4*)(xa0 + k0))[p];
                    float4 bv = ((const float4*)(wb0 + k0))[p];
                    va[4*p+0] = xv.x; va[4*p+1] = xv.y; va[4*p+2] = xv.z; va[4*p+3] = xv.w;
                    vb[4*p+0] = bv.x; vb[4*p+1] = bv.y; vb[4*p+2] = bv.z; vb[4*p+3] = bv.w;
                }
            } else {
                #pragma unroll
                for (int j = 0; j < 16; ++j) { va[j] = 0.f; vb[j] = 0.f; }
            }
            short8 ahi[2], alo[2], bhi[2], blo[2];
            #pragma unroll
            for (int j = 0; j < 16; ++j) {
                short h1 = f2bf(va[j]);
                short l1 = f2bf(va[j] - bf2f(h1));
                short h2 = f2bf(vb[j]);
                short l2 = f2bf(vb[j] - bf2f(h2));
                ahi[j >> 3][j & 7] = h1;  alo[j >> 3][j & 7] = l1;
                bhi[j >> 3][j & 7] = h2;  blo[j >> 3][j & 7] = l2;
            }
            const int base = srow * LDK + kq;
            *(short8*)&Ah[base] = ahi[0];  *(short8*)&Ah[base + 8] = ahi[1];
            *(short8*)&Al[base] = alo[0];  *(short8*)&Al[base + 8] = alo[1];
            *(short8*)&Bh[base] = bhi[0];  *(short8*)&Bh[base + 8] = bhi[1];
            *(short8*)&Bl[base] = blo[0];  *(short8*)&Bl[base + 8] = blo[1];
        }
        __syncthreads();

        short8 bhf[4], blf[4];
        #pragma unroll
        for (int fj = 0; fj < 4; ++fj) {
            const int off = (cb + fj * 16 + lm) * LDK + q * 8;
            bhf[fj] = *(const short8*)&Bh[off];
            blf[fj] = *(const short8*)&Bl[off];
        }
        #pragma unroll
        for (int fi = 0; fi < 4; ++fi) {
            const int off = (rb + fi * 16 + lm) * LDK + q * 8;
            short8 ah = *(const short8*)&Ah[off];
            short8 al = *(const short8*)&Al[off];
            #pragma unroll
            for (int fj = 0; fj < 4; ++fj) {
                acc[fi][fj] = __builtin_amdgcn_mfma_f32_16x16x32_bf16(ah, bhf[fj], acc[fi][fj], 0, 0, 0);
                acc[fi][fj] = __builtin_amdgcn_mfma_f32_16x16x32_bf16(ah, blf[fj], acc[fi][fj], 0, 0, 0);
                acc[fi][fj] = __builtin_amdgcn_mfma_f32_16x16x32_bf16(al, bhf[fj], acc[fi][fj], 0, 0, 0);
            }
        }
        __syncthreads();
    }

    #pragma unroll
    for (int fj = 0; fj < 4; ++fj) {
        const int col  = bn + cb + fj * 16 + lm;
        const float bias = b1[col];
        #pragma unroll
        for (int fi = 0; fi < 4; ++fi) {
            const int row0 = bm + rb + fi * 16 + q * 4;
            #pragma unroll
            for (int r = 0; r < 4; ++r)
                h[(size_t)(row0 + r) * SYS + col] = acc[fi][fj][r] + bias;
        }
    }
}

// ---------------------------------------------------------------------------
// RK4 Lorenz-96 + GEMM2 + log_softmax; packed fp32, TWO ROWS PER WAVE.
// Pair j = (rowA[j], rowB[j]); lane n owns elements 16n..16n+15 of both rows
// as 16 v2f. A +1 element shift is a pure lane rotate for both components:
// circular wrap is natural, NO component-swap cndmasks (was 24/step), and
// 6 ds_bpermutes per deriv now serve 2 rows (DS per row halved).
// State: X+acc+T = 48 v2f ~ 116 VGPR -> 4 waves/SIMD, grid exactly fills.
// ---------------------------------------------------------------------------
__global__ __launch_bounds__(256, 4) void rk4_kernel(
    const float* __restrict__ hbuf, const float* __restrict__ W2,
    const float* __restrict__ b2, float* __restrict__ out)
{
    const int lane = threadIdx.x & 63;
    const int w    = threadIdx.x >> 6;
    const int rowA = blockIdx.x * 8 + w * 2;
    const int rowB = rowA + 1;

    const int laneL = (lane + 63) & 63;
    const int laneR = (lane + 1) & 63;

    v2f X[16];
    {
        const float4* a4 = (const float4*)(hbuf + (size_t)rowA * SYS) + lane * 4;
        const float4* b4 = (const float4*)(hbuf + (size_t)rowB * SYS) + lane * 4;
        #pragma unroll
        for (int k = 0; k < 4; ++k) {
            float4 av = a4[k], bv = b4[k];
            X[4*k+0] = mk2(av.x, bv.x);
            X[4*k+1] = mk2(av.y, bv.y);
            X[4*k+2] = mk2(av.z, bv.z);
            X[4*k+3] = mk2(av.w, bv.w);
        }
    }

    const v2f Fv = mk2(FFORCE, FFORCE);
    v2f acc[16], T[16];

    // in-place derivative on y[16] (both rows at once)
    auto deriv_ip = [&](v2f (&y)[16]) {
        v2f r1 = sh2(y[0],  laneR);   // element 16n+16 (wraps 1023->0 naturally)
        v2f l1 = sh2(y[15], laneL);   // element 16n-1
        v2f l2 = sh2(y[14], laneL);   // element 16n-2
        v2f p2 = l2, p1 = l1, cur = y[0];
        #pragma unroll
        for (int i = 0; i < 16; ++i) {
            v2f yp1 = (i < 15) ? y[i + 1] : r1;
            v2f nv  = pkfma(yp1 - p2, p1, Fv - cur);
            p2 = p1; p1 = cur;
            if (i < 15) cur = y[i + 1];
            y[i] = nv;
        }
    };

    const v2f c_half = mk2(0.5f * HSTEP, 0.5f * HSTEP);
    const v2f c_full = mk2(HSTEP, HSTEP);
    const v2f c_two  = mk2(2.0f, 2.0f);
    const v2f c_six  = mk2(HSTEP / 6.0f, HSTEP / 6.0f);

    #pragma unroll 1
    for (int s = 0; s < NSTEP; ++s) {
        // k1 = deriv(X) out-of-place into acc (X stays live)
        {
            v2f r1 = sh2(X[0],  laneR);
            v2f l1 = sh2(X[15], laneL);
            v2f l2 = sh2(X[14], laneL);
            #pragma unroll
            for (int i = 0; i < 16; ++i) {
                v2f yp1 = (i < 15) ? X[i + 1] : r1;
                v2f ym1 = (i > 0)  ? X[i - 1] : l1;
                v2f ym2 = (i > 1)  ? X[i - 2] : ((i == 1) ? l1 : l2);
                acc[i] = pkfma(yp1 - ym2, ym1, Fv - X[i]);
            }
        }
        #pragma unroll
        for (int i = 0; i < 16; ++i) T[i] = pkfma(c_half, acc[i], X[i]);
        deriv_ip(T);                                    // T = k2
        #pragma unroll
        for (int i = 0; i < 16; ++i) {
            acc[i] = pkfma(c_two, T[i], acc[i]);
            T[i]   = pkfma(c_half, T[i], X[i]);
        }
        deriv_ip(T);                                    // T = k3
        #pragma unroll
        for (int i = 0; i < 16; ++i) {
            acc[i] = pkfma(c_two, T[i], acc[i]);
            T[i]   = pkfma(c_full, T[i], X[i]);
        }
        deriv_ip(T);                                    // T = k4
        #pragma unroll
        for (int i = 0; i < 16; ++i)
            X[i] = pkfma(c_six, acc[i] + T[i], X[i]);
    }

    // GEMM2 + log_softmax for both rows (x-comp = rowA, y-comp = rowB)
    v2f l[OUTSZ];
    #pragma unroll
    for (int o = 0; o < OUTSZ; ++o) {
        const float4* w4 = (const float4*)(W2 + (size_t)o * SYS) + lane * 4;
        v2f s2 = mk2(0.f, 0.f);
        #pragma unroll
        for (int k = 0; k < 4; ++k) {
            float4 wv = w4[k];
            s2 = pkfma(X[4*k+0], mk2(wv.x, wv.x), s2);
            s2 = pkfma(X[4*k+1], mk2(wv.y, wv.y), s2);
            s2 = pkfma(X[4*k+2], mk2(wv.z, wv.z), s2);
            s2 = pkfma(X[4*k+3], mk2(wv.w, wv.w), s2);
        }
        #pragma unroll
        for (int dlt = 1; dlt < 64; dlt <<= 1) {
            s2.x += __shfl_xor(s2.x, dlt);
            s2.y += __shfl_xor(s2.y, dlt);
        }
        const float bo = b2[o];
        l[o] = s2 + mk2(bo, bo);
    }

    v2f m = l[0];
    #pragma unroll
    for (int o = 1; o < OUTSZ; ++o) m = __builtin_elementwise_max(m, l[o]);
    v2f ssum = mk2(0.f, 0.f);
    #pragma unroll
    for (int o = 0; o < OUTSZ; ++o) {
        v2f d = l[o] - m;
        ssum = ssum + mk2(__expf(d.x), __expf(d.y));
    }
    const v2f lse = m + mk2(__logf(ssum.x), __logf(ssum.y));

    float vA = l[0].x - lse.x;
    float vB = l[0].y - lse.y;
    #pragma unroll
    for (int o = 1; o < OUTSZ; ++o) {
        if (lane == o) { vA = l[o].x - lse.x; vB = l[o].y - lse.y; }
    }
    if (lane < OUTSZ) {
        out[(size_t)rowA * OUTSZ + lane] = vA;
        out[(size_t)rowB * OUTSZ + lane] = vB;
    }
}

extern "C" void kernel_launch(void* const* d_in, const int* in_sizes, int n_in,
                              void* d_out, int out_size, void* d_ws, size_t ws_size,
                              hipStream_t stream)
{
    const float* x  = (const float*)d_in[0];
    const float* W1 = (const float*)d_in[1];
    const float* b1 = (const float*)d_in[2];
    const float* W2 = (const float*)d_in[3];
    const float* b2 = (const float*)d_in[4];
    float* out = (float*)d_out;
    float* h   = (float*)d_ws;   // 8192*1024*4 = 33.5 MB scratch

    dim3 g1(SYS / BNg, BATCH / BMg);   // 8 x 64 = 512 blocks
    gemm1_kernel<<<g1, 256, 0, stream>>>(x, W1, b1, h);

    rk4_kernel<<<BATCH / 8, 256, 0, stream>>>(h, W2, b2, out);  // 1024 blocks, 2 rows/wave
}

// Round 7
// 405.446 us; speedup vs baseline: 1.1292x; 1.0641x over previous
//
#include <hip/hip_runtime.h>
#include <hip/hip_bf16.h>
#include <math.h>

#define BATCH 8192
#define INSZ 784
#define SYS 1024
#define OUTSZ 10
#define NSTEP 100
#define HSTEP 0.01f
#define FFORCE 8.0f

typedef short short8 __attribute__((ext_vector_type(8)));
typedef float float4v __attribute__((ext_vector_type(4)));
typedef float v2f __attribute__((ext_vector_type(2)));

static __device__ __forceinline__ short f2bf(float x) {
    __hip_bfloat16 b = __float2bfloat16(x);   // RNE
    return __builtin_bit_cast(short, b);
}
static __device__ __forceinline__ float bf2f(short s) {
    unsigned int u = ((unsigned int)(unsigned short)s) << 16;
    return __builtin_bit_cast(float, u);
}

static __device__ __forceinline__ v2f pkfma(v2f a, v2f b, v2f c) {
    return __builtin_elementwise_fma(a, b, c);
}
static __device__ __forceinline__ v2f mk2(float x, float y) {
    v2f r; r.x = x; r.y = y; return r;
}
// halo transport on the DS pipe (overlaps with VALU; DPP regressed — r5)
static __device__ __forceinline__ v2f sh2(v2f v, int ln) {
    v2f r; r.x = __shfl(v.x, ln); r.y = __shfl(v.y, ln); return r;
}

// ---------------------------------------------------------------------------
// GEMM1 (unchanged from round 2): h = x @ W1^T + b1, split-bf16 MFMA.
// ---------------------------------------------------------------------------
#define BMg 128
#define BNg 128
#define BKg 32
#define LDK 40

__global__ __launch_bounds__(256, 3) void gemm1_kernel(
    const float* __restrict__ x, const float* __restrict__ W1,
    const float* __restrict__ b1, float* __restrict__ h)
{
    __shared__ short Ah[BMg * LDK], Al[BMg * LDK];
    __shared__ short Bh[BNg * LDK], Bl[BNg * LDK];

    const int t  = threadIdx.x;
    const int bm = blockIdx.y * BMg;
    const int bn = blockIdx.x * BNg;

    const int srow = t >> 1;
    const int kq   = (t & 1) * 16;

    const int wv   = t >> 6;
    const int lane = t & 63;
    const int lm   = lane & 15;
    const int q    = lane >> 4;
    const int rb   = (wv & 1) * 64;
    const int cb   = (wv >> 1) * 64;

    float4v acc[4][4];
    #pragma unroll
    for (int i = 0; i < 4; ++i)
        #pragma unroll
        for (int j = 0; j < 4; ++j) {
            acc[i][j][0] = 0.f; acc[i][j][1] = 0.f;
            acc[i][j][2] = 0.f; acc[i][j][3] = 0.f;
        }

    const float* xa0 = x  + (size_t)(bm + srow) * INSZ + kq;
    const float* wb0 = W1 + (size_t)(bn + srow) * INSZ + kq;

    for (int it = 0; it < 25; ++it) {
        const int k0 = it * BKg;
        {
            const bool valid = (k0 + kq) < INSZ;
            float va[16], vb[16];
            if (valid) {
                #pragma unroll
                for (int p = 0; p < 4; ++p) {
                    float4 xv = ((const float4*)(xa0 + k0))[p];
                    float4 bv = ((const float4*)(wb0 + k0))[p];
                    va[4*p+0] = xv.x; va[4*p+1] = xv.y; va[4*p+2] = xv.z; va[4*p+3] = xv.w;
                    vb[4*p+0] = bv.x; vb[4*p+1] = bv.y; vb[4*p+2] = bv.z; vb[4*p+3] = bv.w;
                }
            } else {
                #pragma unroll
                for (int j = 0; j < 16; ++j) { va[j] = 0.f; vb[j] = 0.f; }
            }
            short8 ahi[2], alo[2], bhi[2], blo[2];
            #pragma unroll
            for (int j = 0; j < 16; ++j) {
                short h1 = f2bf(va[j]);
                short l1 = f2bf(va[j] - bf2f(h1));
                short h2 = f2bf(vb[j]);
                short l2 = f2bf(vb[j] - bf2f(h2));
                ahi[j >> 3][j & 7] = h1;  alo[j >> 3][j & 7] = l1;
                bhi[j >> 3][j & 7] = h2;  blo[j >> 3][j & 7] = l2;
            }
            const int base = srow * LDK + kq;
            *(short8*)&Ah[base] = ahi[0];  *(short8*)&Ah[base + 8] = ahi[1];
            *(short8*)&Al[base] = alo[0];  *(short8*)&Al[base + 8] = alo[1];
            *(short8*)&Bh[base] = bhi[0];  *(short8*)&Bh[base + 8] = bhi[1];
            *(short8*)&Bl[base] = blo[0];  *(short8*)&Bl[base + 8] = blo[1];
        }
        __syncthreads();

        short8 bhf[4], blf[4];
        #pragma unroll
        for (int fj = 0; fj < 4; ++fj) {
            const int off = (cb + fj * 16 + lm) * LDK + q * 8;
            bhf[fj] = *(const short8*)&Bh[off];
            blf[fj] = *(const short8*)&Bl[off];
        }
        #pragma unroll
        for (int fi = 0; fi < 4; ++fi) {
            const int off = (rb + fi * 16 + lm) * LDK + q * 8;
            short8 ah = *(const short8*)&Ah[off];
            short8 al = *(const short8*)&Al[off];
            #pragma unroll
            for (int fj = 0; fj < 4; ++fj) {
                acc[fi][fj] = __builtin_amdgcn_mfma_f32_16x16x32_bf16(ah, bhf[fj], acc[fi][fj], 0, 0, 0);
                acc[fi][fj] = __builtin_amdgcn_mfma_f32_16x16x32_bf16(ah, blf[fj], acc[fi][fj], 0, 0, 0);
                acc[fi][fj] = __builtin_amdgcn_mfma_f32_16x16x32_bf16(al, bhf[fj], acc[fi][fj], 0, 0, 0);
            }
        }
        __syncthreads();
    }

    #pragma unroll
    for (int fj = 0; fj < 4; ++fj) {
        const int col  = bn + cb + fj * 16 + lm;
        const float bias = b1[col];
        #pragma unroll
        for (int fi = 0; fi < 4; ++fi) {
            const int row0 = bm + rb + fi * 16 + q * 4;
            #pragma unroll
            for (int r = 0; r < 4; ++r)
                h[(size_t)(row0 + r) * SYS + col] = acc[fi][fj][r] + bias;
        }
    }
}

// ---------------------------------------------------------------------------
// RK4 Lorenz-96 + GEMM2 + log_softmax; packed fp32, two rows per wave,
// SOFTWARE-PIPELINED HALOS: every stage computes boundary elements (0,14,15)
// of the next deriv input first, issues the 3 shuffles, then does the 13
// interior updates + 13 interior deriv elements (~200 cyc of cover) before
// the first DS consume. k1's halos are issued at the previous step's tail.
// Arithmetic per element identical to r6 (same operands, same FP order).
// ---------------------------------------------------------------------------
__global__ __launch_bounds__(256, 4) void rk4_kernel(
    const float* __restrict__ hbuf, const float* __restrict__ W2,
    const float* __restrict__ b2, float* __restrict__ out)
{
    const int lane = threadIdx.x & 63;
    const int w    = threadIdx.x >> 6;
    const int rowA = blockIdx.x * 8 + w * 2;
    const int rowB = rowA + 1;

    const int laneL = (lane + 63) & 63;
    const int laneR = (lane + 1) & 63;

    v2f X[16];
    {
        const float4* a4 = (const float4*)(hbuf + (size_t)rowA * SYS) + lane * 4;
        const float4* b4 = (const float4*)(hbuf + (size_t)rowB * SYS) + lane * 4;
        #pragma unroll
        for (int k = 0; k < 4; ++k) {
            float4 av = a4[k], bv = b4[k];
            X[4*k+0] = mk2(av.x, bv.x);
            X[4*k+1] = mk2(av.y, bv.y);
            X[4*k+2] = mk2(av.z, bv.z);
            X[4*k+3] = mk2(av.w, bv.w);
        }
    }

    const v2f Fv     = mk2(FFORCE, FFORCE);
    const v2f c_half = mk2(0.5f * HSTEP, 0.5f * HSTEP);
    const v2f c_full = mk2(HSTEP, HSTEP);
    const v2f c_two  = mk2(2.0f, 2.0f);
    const v2f c_six  = mk2(HSTEP / 6.0f, HSTEP / 6.0f);

    v2f acc[16], T[16];

    // in-place deriv on y[16] with pre-issued halos; interior first, boundary
    // (the only DS consumers) last.
    auto deriv_ip = [&](v2f (&y)[16], v2f r1, v2f l1, v2f l2) {
        v2f y0o = y[0], y1o = y[1], y2o = y[2];
        v2f d0 = Fv - y[0], d1 = Fv - y[1], d15 = Fv - y[15];
        v2f p2 = y0o, p1 = y1o, cur = y[2];
        #pragma unroll
        for (int i = 2; i < 15; ++i) {
            v2f yp1 = (i < 14) ? y[i + 1] : y[15];
            v2f nv  = pkfma(yp1 - p2, p1, Fv - cur);
            p2 = p1; p1 = cur;
            if (i < 14) cur = y[i + 1];
            y[i] = nv;
        }
        y[15] = pkfma(r1 - p2, p1, d15);      // first DS consume (waitcnt here)
        y[1]  = pkfma(y2o - l1, y0o, d1);
        y[0]  = pkfma(y1o - l2, l1, d0);
    };

    // k1 halos on X, issued at step tail (and once before the loop)
    v2f r1x = sh2(X[0],  laneR);
    v2f l1x = sh2(X[15], laneL);
    v2f l2x = sh2(X[14], laneL);

    #pragma unroll 1
    for (int s = 0; s < NSTEP; ++s) {
        // ---- k1 = deriv(X) out-of-place into acc (X intact) ----
        #pragma unroll
        for (int i = 2; i < 15; ++i)
            acc[i] = pkfma(X[i + 1] - X[i - 2], X[i - 1], Fv - X[i]);
        acc[15] = pkfma(r1x - X[13], X[14], Fv - X[15]);
        acc[1]  = pkfma(X[2] - l1x, X[0],  Fv - X[1]);
        acc[0]  = pkfma(X[1] - l2x, l1x,   Fv - X[0]);

        // ---- T = X + h/2 * k1 ; boundary first, issue k2 halos ----
        T[14] = pkfma(c_half, acc[14], X[14]);
        T[15] = pkfma(c_half, acc[15], X[15]);
        T[0]  = pkfma(c_half, acc[0],  X[0]);
        v2f r1 = sh2(T[0],  laneR);
        v2f l1 = sh2(T[15], laneL);
        v2f l2 = sh2(T[14], laneL);
        #pragma unroll
        for (int i = 1; i < 14; ++i) T[i] = pkfma(c_half, acc[i], X[i]);
        deriv_ip(T, r1, l1, l2);                        // T = k2

        // ---- acc += 2*k2 ; T = X + h/2*k2 ; boundary first, issue k3 halos ----
        {
            v2f a;
            a = T[14]; acc[14] = pkfma(c_two, a, acc[14]); T[14] = pkfma(c_half, a, X[14]);
            a = T[15]; acc[15] = pkfma(c_two, a, acc[15]); T[15] = pkfma(c_half, a, X[15]);
            a = T[0];  acc[0]  = pkfma(c_two, a, acc[0]);  T[0]  = pkfma(c_half, a, X[0]);
            r1 = sh2(T[0],  laneR);
            l1 = sh2(T[15], laneL);
            l2 = sh2(T[14], laneL);
            #pragma unroll
            for (int i = 1; i < 14; ++i) {
                a = T[i]; acc[i] = pkfma(c_two, a, acc[i]); T[i] = pkfma(c_half, a, X[i]);
            }
        }
        deriv_ip(T, r1, l1, l2);                        // T = k3

        // ---- acc += 2*k3 ; T = X + h*k3 ; boundary first, issue k4 halos ----
        {
            v2f a;
            a = T[14]; acc[14] = pkfma(c_two, a, acc[14]); T[14] = pkfma(c_full, a, X[14]);
            a = T[15]; acc[15] = pkfma(c_two, a, acc[15]); T[15] = pkfma(c_full, a, X[15]);
            a = T[0];  acc[0]  = pkfma(c_two, a, acc[0]);  T[0]  = pkfma(c_full, a, X[0]);
            r1 = sh2(T[0],  laneR);
            l1 = sh2(T[15], laneL);
            l2 = sh2(T[14], laneL);
            #pragma unroll
            for (int i = 1; i < 14; ++i) {
                a = T[i]; acc[i] = pkfma(c_two, a, acc[i]); T[i] = pkfma(c_full, a, X[i]);
            }
        }
        deriv_ip(T, r1, l1, l2);                        // T = k4

        // ---- X += h/6 * (acc + k4) ; boundary first, issue next k1 halos ----
        X[14] = pkfma(c_six, acc[14] + T[14], X[14]);
        X[15] = pkfma(c_six, acc[15] + T[15], X[15]);
        X[0]  = pkfma(c_six, acc[0]  + T[0],  X[0]);
        r1x = sh2(X[0],  laneR);
        l1x = sh2(X[15], laneL);
        l2x = sh2(X[14], laneL);
        #pragma unroll
        for (int i = 1; i < 14; ++i)
            X[i] = pkfma(c_six, acc[i] + T[i], X[i]);
    }

    // GEMM2 + log_softmax for both rows (x-comp = rowA, y-comp = rowB)
    v2f l[OUTSZ];
    #pragma unroll
    for (int o = 0; o < OUTSZ; ++o) {
        const float4* w4 = (const float4*)(W2 + (size_t)o * SYS) + lane * 4;
        v2f s2 = mk2(0.f, 0.f);
        #pragma unroll
        for (int k = 0; k < 4; ++k) {
            float4 wv = w4[k];
            s2 = pkfma(X[4*k+0], mk2(wv.x, wv.x), s2);
            s2 = pkfma(X[4*k+1], mk2(wv.y, wv.y), s2);
            s2 = pkfma(X[4*k+2], mk2(wv.z, wv.z), s2);
            s2 = pkfma(X[4*k+3], mk2(wv.w, wv.w), s2);
        }
        #pragma unroll
        for (int dlt = 1; dlt < 64; dlt <<= 1) {
            s2.x += __shfl_xor(s2.x, dlt);
            s2.y += __shfl_xor(s2.y, dlt);
        }
        const float bo = b2[o];
        l[o] = s2 + mk2(bo, bo);
    }

    v2f m = l[0];
    #pragma unroll
    for (int o = 1; o < OUTSZ; ++o) m = __builtin_elementwise_max(m, l[o]);
    v2f ssum = mk2(0.f, 0.f);
    #pragma unroll
    for (int o = 0; o < OUTSZ; ++o) {
        v2f d = l[o] - m;
        ssum = ssum + mk2(__expf(d.x), __expf(d.y));
    }
    const v2f lse = m + mk2(__logf(ssum.x), __logf(ssum.y));

    float vA = l[0].x - lse.x;
    float vB = l[0].y - lse.y;
    #pragma unroll
    for (int o = 1; o < OUTSZ; ++o) {
        if (lane == o) { vA = l[o].x - lse.x; vB = l[o].y - lse.y; }
    }
    if (lane < OUTSZ) {
        out[(size_t)rowA * OUTSZ + lane] = vA;
        out[(size_t)rowB * OUTSZ + lane] = vB;
    }
}

extern "C" void kernel_launch(void* const* d_in, const int* in_sizes, int n_in,
                              void* d_out, int out_size, void* d_ws, size_t ws_size,
                              hipStream_t stream)
{
    const float* x  = (const float*)d_in[0];
    const float* W1 = (const float*)d_in[1];
    const float* b1 = (const float*)d_in[2];
    const float* W2 = (const float*)d_in[3];
    const float* b2 = (const float*)d_in[4];
    float* out = (float*)d_out;
    float* h   = (float*)d_ws;   // 8192*1024*4 = 33.5 MB scratch

    dim3 g1(SYS / BNg, BATCH / BMg);   // 8 x 64 = 512 blocks
    gemm1_kernel<<<g1, 256, 0, stream>>>(x, W1, b1, h);

    rk4_kernel<<<BATCH / 8, 256, 0, stream>>>(h, W2, b2, out);  // 1024 blocks, 2 rows/wave
}